// Round 1
// baseline (493.992 us; speedup 1.0000x reference)
//
#include <hip/hip_runtime.h>
#include <hip/hip_bf16.h>
#include <cstdint>
#include <cstddef>

#define B_   8192
#define D_   2048
#define H1_  1024
#define H2_  512
#define G_   512
#define T_   2
#define E_   6
#define EC_  4

typedef __bf16 bf16_t;
typedef __attribute__((ext_vector_type(8))) __bf16 bf16x8;
typedef __attribute__((ext_vector_type(4))) float f32x4;

// ---------------------------------------------------------------------------
// async global->LDS, 16B per lane. LDS dest is wave-uniform base + lane*16.
// ---------------------------------------------------------------------------
__device__ __forceinline__ void gload_lds16(const bf16_t* g, bf16_t* l) {
    __builtin_amdgcn_global_load_lds(
        (const __attribute__((address_space(1))) bf16_t*)g,
        (__attribute__((address_space(3))) bf16_t*)l,
        16, 0, 0);
}

// ---------------------------------------------------------------------------
// cast x (fp32) -> bf16, 8 elems/thread
// ---------------------------------------------------------------------------
__global__ __launch_bounds__(256) void cast_x_kernel(
    const float* __restrict__ src, bf16_t* __restrict__ dst, int n8)
{
    int i = blockIdx.x * blockDim.x + threadIdx.x;
    if (i >= n8) return;
    const float4* s = (const float4*)src + (size_t)i * 2;
    float4 a = s[0], b = s[1];
    bf16x8 o;
    o[0] = (bf16_t)a.x; o[1] = (bf16_t)a.y; o[2] = (bf16_t)a.z; o[3] = (bf16_t)a.w;
    o[4] = (bf16_t)b.x; o[5] = (bf16_t)b.y; o[6] = (bf16_t)b.z; o[7] = (bf16_t)b.w;
    *(bf16x8*)(dst + (size_t)i * 8) = o;
}

// ---------------------------------------------------------------------------
// transpose + cast: src (batch, R, C) fp32 -> dst (batch, C, R) bf16
// block (32,8), grid (C/32, R/32, batch)
// ---------------------------------------------------------------------------
__global__ __launch_bounds__(256) void transpose_cast_kernel(
    const float* __restrict__ src, bf16_t* __restrict__ dst, int R, int C)
{
    __shared__ float tile[32][33];
    int bz = blockIdx.z;
    src += (size_t)bz * R * C;
    dst += (size_t)bz * R * C;
    int c0 = blockIdx.x * 32, r0 = blockIdx.y * 32;
    int tx = threadIdx.x, ty = threadIdx.y;
#pragma unroll
    for (int i = 0; i < 32; i += 8)
        tile[ty + i][tx] = src[(size_t)(r0 + ty + i) * C + (c0 + tx)];
    __syncthreads();
#pragma unroll
    for (int i = 0; i < 32; i += 8)
        dst[(size_t)(c0 + ty + i) * R + (r0 + tx)] = (bf16_t)tile[tx][ty + i];
}

// ---------------------------------------------------------------------------
// C(M,N) = relu(A(M,K) * Bt(N,K)^T + bias(N)), all bf16 in / bf16 out,
// fp32 MFMA accumulate. m97 structure: 128x128 tile, BK=32, 4 waves,
// global_load_lds width 16, 2 barriers per K-step.
// batch via blockIdx.z: A += z*strideA, Bt += z*N*K, bias += z*N, C += z*M*N.
// ---------------------------------------------------------------------------
__global__ __launch_bounds__(256) void gemm_bt_bias_relu(
    const bf16_t* __restrict__ A, const bf16_t* __restrict__ Bt,
    const float* __restrict__ bias, bf16_t* __restrict__ C,
    int M, int N, int K, long long strideA)
{
    const int e = blockIdx.z;
    A    += (size_t)e * (size_t)strideA;
    Bt   += (size_t)e * (size_t)N * (size_t)K;
    bias += (size_t)e * (size_t)N;
    C    += (size_t)e * (size_t)M * (size_t)N;

    __shared__ bf16_t lsA[128 * 32];
    __shared__ bf16_t lsB[128 * 32];

    const int tid  = threadIdx.x;
    const int lane = tid & 63;
    const int wave = tid >> 6;           // 0..3
    const int wr   = wave >> 1;          // 2x2 wave grid, 64x64 per wave
    const int wc   = wave & 1;
    const int row0 = blockIdx.y * 128;
    const int col0 = blockIdx.x * 128;

    // staging source coords: chunk q = r*4+wave covers shorts [q*512, q*512+512)
    // of the row-major [128][32] tile; lane covers 8 shorts (16B).
    int sRow[2], sCol[2];
#pragma unroll
    for (int r = 0; r < 2; ++r) {
        int s = (r * 4 + wave) * 512 + lane * 8;
        sRow[r] = s >> 5;
        sCol[r] = s & 31;
    }

    f32x4 acc[4][4];
#pragma unroll
    for (int m = 0; m < 4; ++m)
#pragma unroll
        for (int n = 0; n < 4; ++n)
            acc[m][n] = (f32x4){0.f, 0.f, 0.f, 0.f};

    const int aRowBase = wr * 64 + (lane & 15);
    const int bRowBase = wc * 64 + (lane & 15);
    const int kcol     = (lane >> 4) * 8;

    for (int k0 = 0; k0 < K; k0 += 32) {
#pragma unroll
        for (int r = 0; r < 2; ++r) {
            gload_lds16(A  + (size_t)(row0 + sRow[r]) * K + (k0 + sCol[r]),
                        lsA + (r * 4 + wave) * 512);
            gload_lds16(Bt + (size_t)(col0 + sRow[r]) * K + (k0 + sCol[r]),
                        lsB + (r * 4 + wave) * 512);
        }
        __syncthreads();   // drains vmcnt -> staging visible

        bf16x8 af[4], bfr[4];
#pragma unroll
        for (int m = 0; m < 4; ++m)
            af[m] = *(const bf16x8*)&lsA[(aRowBase + m * 16) * 32 + kcol];
#pragma unroll
        for (int n = 0; n < 4; ++n)
            bfr[n] = *(const bf16x8*)&lsB[(bRowBase + n * 16) * 32 + kcol];

#pragma unroll
        for (int m = 0; m < 4; ++m)
#pragma unroll
            for (int n = 0; n < 4; ++n)
                acc[m][n] = __builtin_amdgcn_mfma_f32_16x16x32_bf16(
                                af[m], bfr[n], acc[m][n], 0, 0, 0);
        __syncthreads();   // all waves done reading before next stage
    }

    // epilogue: C/D layout col = lane&15, row = (lane>>4)*4 + j   [m89-verified]
    const int crow = row0 + wr * 64 + ((lane >> 4) << 2);
    const int ccol = col0 + wc * 64 + (lane & 15);
#pragma unroll
    for (int n = 0; n < 4; ++n) {
        int cc = ccol + n * 16;
        float bv = bias[cc];
#pragma unroll
        for (int m = 0; m < 4; ++m) {
            int rb = crow + m * 16;
#pragma unroll
            for (int j = 0; j < 4; ++j) {
                float v = acc[m][n][j] + bv;
                v = v > 0.f ? v : 0.f;
                C[(size_t)(rb + j) * N + cc] = (bf16_t)v;
            }
        }
    }
}

// ---------------------------------------------------------------------------
// gate: logits[t,b,e] = sum_g g[t,b,g] * Wgs[t,g,e]; softmax over e (EC=4).
// one wave per (t,b) row: 64 lanes x 8 g-elements each.
// ---------------------------------------------------------------------------
__global__ __launch_bounds__(256) void gate_kernel(
    const bf16_t* __restrict__ g, const float* __restrict__ Wgs,
    float* __restrict__ gate)
{
    int wid  = blockIdx.x * 4 + (threadIdx.x >> 6);   // (t*B + b)
    int lane = threadIdx.x & 63;
    int t = wid >> 13;                                 // B_ = 8192
    const bf16_t* grow = g + (size_t)wid * G_;
    bf16x8 gv = *(const bf16x8*)&grow[lane * 8];
    const float* W = Wgs + (size_t)t * G_ * EC_;
    float a0 = 0.f, a1 = 0.f, a2 = 0.f, a3 = 0.f;
#pragma unroll
    for (int i = 0; i < 8; ++i) {
        float gvf = (float)gv[i];
        const float4 w = *(const float4*)&W[(size_t)(lane * 8 + i) * 4];
        a0 += gvf * w.x; a1 += gvf * w.y; a2 += gvf * w.z; a3 += gvf * w.w;
    }
#pragma unroll
    for (int off = 32; off; off >>= 1) {
        a0 += __shfl_xor(a0, off);
        a1 += __shfl_xor(a1, off);
        a2 += __shfl_xor(a2, off);
        a3 += __shfl_xor(a3, off);
    }
    if (lane == 0) {
        float m  = fmaxf(fmaxf(a0, a1), fmaxf(a2, a3));
        float e0 = expf(a0 - m), e1 = expf(a1 - m), e2 = expf(a2 - m), e3 = expf(a3 - m);
        float inv = 1.f / (e0 + e1 + e2 + e3);
        *(float4*)&gate[(size_t)wid * 4] = make_float4(e0 * inv, e1 * inv, e2 * inv, e3 * inv);
    }
}

// ---------------------------------------------------------------------------
// combine: out[t,b,o] = sum_j gate[t,b,j] * h2[IDX[t][j], b, o]
// IDX[t] = {2t, 2t+1, 4, 5}. 8 outputs per thread.
// ---------------------------------------------------------------------------
__global__ __launch_bounds__(256) void combine_kernel(
    const bf16_t* __restrict__ h2, const float* __restrict__ gate,
    float* __restrict__ out)
{
    size_t idx = (size_t)blockIdx.x * 256 + threadIdx.x;
    size_t tb  = idx >> 6;                 // H2/8 = 64 chunks per row
    int    o0  = (int)(idx & 63) * 8;
    int    t   = (int)(tb >> 13);
    size_t b   = tb & (size_t)(B_ - 1);
    const float4 gv = *(const float4*)&gate[tb * 4];
    const bf16x8 v0 = *(const bf16x8*)&h2[((size_t)(2 * t)     * B_ + b) * H2_ + o0];
    const bf16x8 v1 = *(const bf16x8*)&h2[((size_t)(2 * t + 1) * B_ + b) * H2_ + o0];
    const bf16x8 v2 = *(const bf16x8*)&h2[((size_t)4           * B_ + b) * H2_ + o0];
    const bf16x8 v3 = *(const bf16x8*)&h2[((size_t)5           * B_ + b) * H2_ + o0];
    float r[8];
#pragma unroll
    for (int i = 0; i < 8; ++i)
        r[i] = gv.x * (float)v0[i] + gv.y * (float)v1[i]
             + gv.z * (float)v2[i] + gv.w * (float)v3[i];
    float4* op = (float4*)&out[tb * H2_ + o0];
    op[0] = make_float4(r[0], r[1], r[2], r[3]);
    op[1] = make_float4(r[4], r[5], r[6], r[7]);
}

// ---------------------------------------------------------------------------
extern "C" void kernel_launch(void* const* d_in, const int* in_sizes, int n_in,
                              void* d_out, int out_size, void* d_ws, size_t ws_size,
                              hipStream_t stream)
{
    const float* x   = (const float*)d_in[0];
    const float* We1 = (const float*)d_in[1];
    const float* be1 = (const float*)d_in[2];
    const float* We2 = (const float*)d_in[3];
    const float* be2 = (const float*)d_in[4];
    const float* Wg1 = (const float*)d_in[5];
    const float* bg1 = (const float*)d_in[6];
    const float* Wgs = (const float*)d_in[7];
    float* out = (float*)d_out;

    char* ws = (char*)d_ws;
    bf16_t* x_bf = (bf16_t*)ws;  ws += (size_t)B_ * D_ * 2;            //  33.6 MB
    bf16_t* w1t  = (bf16_t*)ws;  ws += (size_t)E_ * H1_ * D_ * 2;      //  25.2 MB
    bf16_t* w2t  = (bf16_t*)ws;  ws += (size_t)E_ * H2_ * H1_ * 2;     //   6.3 MB
    bf16_t* wgt  = (bf16_t*)ws;  ws += (size_t)T_ * G_ * D_ * 2;       //   4.2 MB
    bf16_t* h1   = (bf16_t*)ws;  ws += (size_t)E_ * B_ * H1_ * 2;      // 100.7 MB
    bf16_t* h2   = (bf16_t*)ws;  ws += (size_t)E_ * B_ * H2_ * 2;      //  50.3 MB
    bf16_t* gbuf = (bf16_t*)ws;  ws += (size_t)T_ * B_ * G_ * 2;       //  16.8 MB
    float*  gate = (float*)ws;   ws += (size_t)T_ * B_ * EC_ * 4;      //   0.3 MB

    // 1) casts / transposes
    cast_x_kernel<<<(B_ * D_ / 8) / 256, 256, 0, stream>>>(x, x_bf, B_ * D_ / 8);
    dim3 tb(32, 8);
    transpose_cast_kernel<<<dim3(H1_ / 32, D_ / 32, E_),  tb, 0, stream>>>(We1, w1t, D_,  H1_);
    transpose_cast_kernel<<<dim3(H2_ / 32, H1_ / 32, E_), tb, 0, stream>>>(We2, w2t, H1_, H2_);
    transpose_cast_kernel<<<dim3(G_ / 32, D_ / 32, T_),   tb, 0, stream>>>(Wg1, wgt, D_,  G_);

    // 2) expert MLP + gate GEMMs (bf16 MFMA, fused bias+relu)
    gemm_bt_bias_relu<<<dim3(H1_ / 128, B_ / 128, E_), 256, 0, stream>>>(
        x_bf, w1t, be1, h1, B_, H1_, D_, 0LL);
    gemm_bt_bias_relu<<<dim3(H2_ / 128, B_ / 128, E_), 256, 0, stream>>>(
        h1, w2t, be2, h2, B_, H2_, H1_, (long long)B_ * H1_);
    gemm_bt_bias_relu<<<dim3(G_ / 128, B_ / 128, T_), 256, 0, stream>>>(
        x_bf, wgt, bg1, gbuf, B_, G_, D_, 0LL);

    // 3) gate softmax + final combine
    gate_kernel<<<(T_ * B_) / 4, 256, 0, stream>>>(gbuf, Wgs, gate);
    combine_kernel<<<((size_t)T_ * B_ * H2_ / 8) / 256, 256, 0, stream>>>(h2, gate, out);
}

// Round 2
// 419.395 us; speedup vs baseline: 1.1779x; 1.1779x over previous
//
#include <hip/hip_runtime.h>
#include <hip/hip_bf16.h>
#include <cstdint>
#include <cstddef>

#define B_   8192
#define D_   2048
#define H1_  1024
#define H2_  512
#define G_   512
#define T_   2
#define E_   6
#define EC_  4

typedef __bf16 bf16_t;
typedef __attribute__((ext_vector_type(8))) __bf16 bf16x8;
typedef __attribute__((ext_vector_type(4))) float f32x4;

// ---------------------------------------------------------------------------
// async global->LDS, 16B per lane. LDS dest is wave-uniform base + lane*16.
// ---------------------------------------------------------------------------
__device__ __forceinline__ void gload_lds16(const bf16_t* g, bf16_t* l) {
    __builtin_amdgcn_global_load_lds(
        (const __attribute__((address_space(1))) bf16_t*)g,
        (__attribute__((address_space(3))) bf16_t*)l,
        16, 0, 0);
}

// ---------------------------------------------------------------------------
// cast x (fp32) -> bf16, 8 elems/thread
// ---------------------------------------------------------------------------
__global__ __launch_bounds__(256) void cast_x_kernel(
    const float* __restrict__ src, bf16_t* __restrict__ dst, int n8)
{
    int i = blockIdx.x * blockDim.x + threadIdx.x;
    if (i >= n8) return;
    const float4* s = (const float4*)src + (size_t)i * 2;
    float4 a = s[0], b = s[1];
    bf16x8 o;
    o[0] = (bf16_t)a.x; o[1] = (bf16_t)a.y; o[2] = (bf16_t)a.z; o[3] = (bf16_t)a.w;
    o[4] = (bf16_t)b.x; o[5] = (bf16_t)b.y; o[6] = (bf16_t)b.z; o[7] = (bf16_t)b.w;
    *(bf16x8*)(dst + (size_t)i * 8) = o;
}

// ---------------------------------------------------------------------------
// transpose + cast: src (batch, R, C) fp32 -> dst (batch, C, R) bf16
// ---------------------------------------------------------------------------
__global__ __launch_bounds__(256) void transpose_cast_kernel(
    const float* __restrict__ src, bf16_t* __restrict__ dst, int R, int C)
{
    __shared__ float tile[32][33];
    int bz = blockIdx.z;
    src += (size_t)bz * R * C;
    dst += (size_t)bz * R * C;
    int c0 = blockIdx.x * 32, r0 = blockIdx.y * 32;
    int tx = threadIdx.x, ty = threadIdx.y;
#pragma unroll
    for (int i = 0; i < 32; i += 8)
        tile[ty + i][tx] = src[(size_t)(r0 + ty + i) * C + (c0 + tx)];
    __syncthreads();
#pragma unroll
    for (int i = 0; i < 32; i += 8)
        dst[(size_t)(c0 + ty + i) * R + (r0 + tx)] = (bf16_t)tile[tx][ty + i];
}

// ---------------------------------------------------------------------------
// 256x256-tile phase-split GEMM: C = relu(A(M,K) * Bt(N,K)^T + bias), bf16.
// 8 waves (2M x 4N), per-wave 128x64 output. BK=32, 4 LDS buffers (128 KB),
// depth-3 staging pipeline with counted vmcnt (T3+T4), chunk-XOR LDS swizzle
// applied on BOTH global-source and ds_read sides (T2, rule #21),
// s_setprio around MFMA clusters (T5), XCD-aware block swizzle (T1).
// Requires: M%256==0, N%256==0, K%32==0, K/32 >= 4, gridX*gridY % 8 == 0.
// ---------------------------------------------------------------------------
__global__ __launch_bounds__(512, 2) void gemm256_bt_bias_relu(
    const bf16_t* __restrict__ A, const bf16_t* __restrict__ Bt,
    const float* __restrict__ bias, bf16_t* __restrict__ C,
    int M, int N, int K, long long strideA)
{
    const int e = blockIdx.z;
    A    += (size_t)e * (size_t)strideA;
    Bt   += (size_t)e * (size_t)N * (size_t)K;
    bias += (size_t)e * (size_t)N;
    C    += (size_t)e * (size_t)M * (size_t)N;

    // T1: XCD swizzle within this z-slice (nwg % 8 == 0 guaranteed by launch)
    const int gx  = gridDim.x;
    const int nwg = gx * gridDim.y;
    const int lin = blockIdx.y * gx + blockIdx.x;
    const int swz = (lin & 7) * (nwg >> 3) + (lin >> 3);
    const int bx  = swz % gx;
    const int by  = swz / gx;
    const int row0 = by * 256;
    const int col0 = bx * 256;

    __shared__ bf16_t lsA[4][8192];   // 4 buffers x 256 rows x 32 (16 KB each)
    __shared__ bf16_t lsB[4][8192];

    const int tid  = threadIdx.x;
    const int lane = tid & 63;
    const int wave = tid >> 6;        // 0..7
    const int wr   = wave >> 2;       // 0..1 : M-half
    const int wc   = wave & 3;        // 0..3 : N-quarter

    // ---- staging geometry ---------------------------------------------------
    // tile = 256 rows x 4 chunks of 16B. slot idx = l*512 + tid, l in {0,1}.
    // phys slot (r, cp) sources logical chunk c = cp ^ ((r>>1)&3)  [involution]
    size_t off[2];       // global element offset from (row0|col0, k0)
    int    ldsOff[2];    // wave-uniform LDS element base per load
#pragma unroll
    for (int l = 0; l < 2; ++l) {
        int idx = l * 512 + tid;
        int r   = idx >> 2;
        int c   = (idx & 3) ^ ((idx >> 3) & 3);
        off[l]    = (size_t)r * (size_t)K + c * 8;
        ldsOff[l] = l * 4096 + wave * 512;   // (l*512 + wave*64) slots * 8 elems
    }
    const bf16_t* gA = A  + (size_t)row0 * (size_t)K;
    const bf16_t* gB = Bt + (size_t)col0 * (size_t)K;

    // ---- fragment read addressing (swizzled) --------------------------------
    // logical: row rm, k-chunk (lane>>4); phys chunk = (lane>>4) ^ ((rm>>1)&3),
    // and (rm>>1)&3 == (lane>>1)&3 since row bases are multiples of 16.
    const int arow = wr * 128 + (lane & 15);
    const int brow = wc * 64  + (lane & 15);
    const int kch  = (((lane >> 4) ^ ((lane >> 1) & 3)) << 3);

    f32x4 acc[8][4];
#pragma unroll
    for (int m = 0; m < 8; ++m)
#pragma unroll
        for (int n = 0; n < 4; ++n)
            acc[m][n] = (f32x4){0.f, 0.f, 0.f, 0.f};

    const int nt = K >> 5;            // K/32 tiles, nt >= 4

    // ---- prologue: stage tiles 0,1,2 ---------------------------------------
#pragma unroll
    for (int pt = 0; pt < 3; ++pt) {
        const size_t kk = (size_t)pt * 32;
#pragma unroll
        for (int l = 0; l < 2; ++l)
            gload_lds16(gA + kk + off[l], &lsA[pt][ldsOff[l]]);
#pragma unroll
        for (int l = 0; l < 2; ++l)
            gload_lds16(gB + kk + off[l], &lsB[pt][ldsOff[l]]);
    }
    asm volatile("s_waitcnt vmcnt(8)" ::: "memory");   // tile 0 complete
    __builtin_amdgcn_s_barrier();

    // ---- main loop: 2 phases per K-tile ------------------------------------
    for (int t = 0; t < nt; ++t) {
        const int  c  = t & 3;
        const bool st = (t + 3 < nt);
        const int  s  = (t + 3) & 3;
        const size_t kk = (size_t)(t + 3) * 32;

        bf16x8 a[4], b[4];

        // phase 0: frags m=0..3 + all B frags; stage A half of tile t+3
#pragma unroll
        for (int m = 0; m < 4; ++m)
            a[m] = *(const bf16x8*)&lsA[c][(arow + m * 16) * 32 + kch];
#pragma unroll
        for (int n = 0; n < 4; ++n)
            b[n] = *(const bf16x8*)&lsB[c][(brow + n * 16) * 32 + kch];
        if (st) {
#pragma unroll
            for (int l = 0; l < 2; ++l)
                gload_lds16(gA + kk + off[l], &lsA[s][ldsOff[l]]);
        }
        __builtin_amdgcn_sched_barrier(0);
        __builtin_amdgcn_s_barrier();
        __builtin_amdgcn_s_setprio(1);
#pragma unroll
        for (int m = 0; m < 4; ++m)
#pragma unroll
            for (int n = 0; n < 4; ++n)
                acc[m][n] = __builtin_amdgcn_mfma_f32_16x16x32_bf16(
                                a[m], b[n], acc[m][n], 0, 0, 0);
        __builtin_amdgcn_s_setprio(0);
        __builtin_amdgcn_sched_barrier(0);
        __builtin_amdgcn_s_barrier();

        // phase 1: frags m=4..7 (B frags register-resident); stage B half
#pragma unroll
        for (int m = 0; m < 4; ++m)
            a[m] = *(const bf16x8*)&lsA[c][(arow + (m + 4) * 16) * 32 + kch];
        if (st) {
#pragma unroll
            for (int l = 0; l < 2; ++l)
                gload_lds16(gB + kk + off[l], &lsB[s][ldsOff[l]]);
        }
        __builtin_amdgcn_sched_barrier(0);
        __builtin_amdgcn_s_barrier();
        __builtin_amdgcn_s_setprio(1);
#pragma unroll
        for (int m = 0; m < 4; ++m)
#pragma unroll
            for (int n = 0; n < 4; ++n)
                acc[m + 4][n] = __builtin_amdgcn_mfma_f32_16x16x32_bf16(
                                    a[m], b[n], acc[m + 4][n], 0, 0, 0);
        __builtin_amdgcn_s_setprio(0);

        // end-of-tile: counted vmcnt guarantees tile t+1 staged; never 0
        // in steady state (tiles t+2, t+3 stay in flight: 8 loads).
        if (t + 3 < nt) {
            asm volatile("s_waitcnt vmcnt(8)" ::: "memory");
        } else if (t + 3 == nt) {
            asm volatile("s_waitcnt vmcnt(4)" ::: "memory");
        } else if (t + 2 == nt) {
            asm volatile("s_waitcnt vmcnt(0)" ::: "memory");
        }
        __builtin_amdgcn_sched_barrier(0);
        __builtin_amdgcn_s_barrier();
    }

    // ---- epilogue: C/D layout col = lane&15, row = (lane>>4)*4 + j ----------
    const int crb = row0 + wr * 128 + ((lane >> 4) << 2);
    const int ccb = col0 + wc * 64  + (lane & 15);
#pragma unroll
    for (int n = 0; n < 4; ++n) {
        const int cc = ccb + n * 16;
        const float bv = bias[cc];
#pragma unroll
        for (int m = 0; m < 8; ++m) {
            const int rb = crb + m * 16;
#pragma unroll
            for (int j = 0; j < 4; ++j) {
                float v = acc[m][n][j] + bv;
                v = v > 0.f ? v : 0.f;
                C[(size_t)(rb + j) * N + cc] = (bf16_t)v;
            }
        }
    }
}

// ---------------------------------------------------------------------------
// m97-structure 128x128 GEMM (proven in round 1) — kept for the gate GEMM,
// whose 256^2 grid (128 blocks) would leave half the CUs idle.
// ---------------------------------------------------------------------------
__global__ __launch_bounds__(256) void gemm_bt_bias_relu(
    const bf16_t* __restrict__ A, const bf16_t* __restrict__ Bt,
    const float* __restrict__ bias, bf16_t* __restrict__ C,
    int M, int N, int K, long long strideA)
{
    const int e = blockIdx.z;
    A    += (size_t)e * (size_t)strideA;
    Bt   += (size_t)e * (size_t)N * (size_t)K;
    bias += (size_t)e * (size_t)N;
    C    += (size_t)e * (size_t)M * (size_t)N;

    __shared__ bf16_t lsA[128 * 32];
    __shared__ bf16_t lsB[128 * 32];

    const int tid  = threadIdx.x;
    const int lane = tid & 63;
    const int wave = tid >> 6;
    const int wr   = wave >> 1;
    const int wc   = wave & 1;
    const int row0 = blockIdx.y * 128;
    const int col0 = blockIdx.x * 128;

    int sRow[2], sCol[2];
#pragma unroll
    for (int r = 0; r < 2; ++r) {
        int s = (r * 4 + wave) * 512 + lane * 8;
        sRow[r] = s >> 5;
        sCol[r] = s & 31;
    }

    f32x4 acc[4][4];
#pragma unroll
    for (int m = 0; m < 4; ++m)
#pragma unroll
        for (int n = 0; n < 4; ++n)
            acc[m][n] = (f32x4){0.f, 0.f, 0.f, 0.f};

    const int aRowBase = wr * 64 + (lane & 15);
    const int bRowBase = wc * 64 + (lane & 15);
    const int kcol     = (lane >> 4) * 8;

    for (int k0 = 0; k0 < K; k0 += 32) {
#pragma unroll
        for (int r = 0; r < 2; ++r) {
            gload_lds16(A  + (size_t)(row0 + sRow[r]) * K + (k0 + sCol[r]),
                        lsA + (r * 4 + wave) * 512);
            gload_lds16(Bt + (size_t)(col0 + sRow[r]) * K + (k0 + sCol[r]),
                        lsB + (r * 4 + wave) * 512);
        }
        __syncthreads();

        bf16x8 af[4], bfr[4];
#pragma unroll
        for (int m = 0; m < 4; ++m)
            af[m] = *(const bf16x8*)&lsA[(aRowBase + m * 16) * 32 + kcol];
#pragma unroll
        for (int n = 0; n < 4; ++n)
            bfr[n] = *(const bf16x8*)&lsB[(bRowBase + n * 16) * 32 + kcol];

#pragma unroll
        for (int m = 0; m < 4; ++m)
#pragma unroll
            for (int n = 0; n < 4; ++n)
                acc[m][n] = __builtin_amdgcn_mfma_f32_16x16x32_bf16(
                                af[m], bfr[n], acc[m][n], 0, 0, 0);
        __syncthreads();
    }

    const int crow = row0 + wr * 64 + ((lane >> 4) << 2);
    const int ccol = col0 + wc * 64 + (lane & 15);
#pragma unroll
    for (int n = 0; n < 4; ++n) {
        int cc = ccol + n * 16;
        float bv = bias[cc];
#pragma unroll
        for (int m = 0; m < 4; ++m) {
            int rb = crow + m * 16;
#pragma unroll
            for (int j = 0; j < 4; ++j) {
                float v = acc[m][n][j] + bv;
                v = v > 0.f ? v : 0.f;
                C[(size_t)(rb + j) * N + cc] = (bf16_t)v;
            }
        }
    }
}

// ---------------------------------------------------------------------------
// gate: logits[t,b,e] = sum_g g[t,b,g] * Wgs[t,g,e]; softmax over e (EC=4).
// ---------------------------------------------------------------------------
__global__ __launch_bounds__(256) void gate_kernel(
    const bf16_t* __restrict__ g, const float* __restrict__ Wgs,
    float* __restrict__ gate)
{
    int wid  = blockIdx.x * 4 + (threadIdx.x >> 6);
    int lane = threadIdx.x & 63;
    int t = wid >> 13;
    const bf16_t* grow = g + (size_t)wid * G_;
    bf16x8 gv = *(const bf16x8*)&grow[lane * 8];
    const float* W = Wgs + (size_t)t * G_ * EC_;
    float a0 = 0.f, a1 = 0.f, a2 = 0.f, a3 = 0.f;
#pragma unroll
    for (int i = 0; i < 8; ++i) {
        float gvf = (float)gv[i];
        const float4 w = *(const float4*)&W[(size_t)(lane * 8 + i) * 4];
        a0 += gvf * w.x; a1 += gvf * w.y; a2 += gvf * w.z; a3 += gvf * w.w;
    }
#pragma unroll
    for (int off = 32; off; off >>= 1) {
        a0 += __shfl_xor(a0, off);
        a1 += __shfl_xor(a1, off);
        a2 += __shfl_xor(a2, off);
        a3 += __shfl_xor(a3, off);
    }
    if (lane == 0) {
        float m  = fmaxf(fmaxf(a0, a1), fmaxf(a2, a3));
        float e0 = expf(a0 - m), e1 = expf(a1 - m), e2 = expf(a2 - m), e3 = expf(a3 - m);
        float inv = 1.f / (e0 + e1 + e2 + e3);
        *(float4*)&gate[(size_t)wid * 4] = make_float4(e0 * inv, e1 * inv, e2 * inv, e3 * inv);
    }
}

// ---------------------------------------------------------------------------
// combine: out[t,b,o] = sum_j gate[t,b,j] * h2[IDX[t][j], b, o]
// ---------------------------------------------------------------------------
__global__ __launch_bounds__(256) void combine_kernel(
    const bf16_t* __restrict__ h2, const float* __restrict__ gate,
    float* __restrict__ out)
{
    size_t idx = (size_t)blockIdx.x * 256 + threadIdx.x;
    size_t tb  = idx >> 6;
    int    o0  = (int)(idx & 63) * 8;
    int    t   = (int)(tb >> 13);
    size_t b   = tb & (size_t)(B_ - 1);
    const float4 gv = *(const float4*)&gate[tb * 4];
    const bf16x8 v0 = *(const bf16x8*)&h2[((size_t)(2 * t)     * B_ + b) * H2_ + o0];
    const bf16x8 v1 = *(const bf16x8*)&h2[((size_t)(2 * t + 1) * B_ + b) * H2_ + o0];
    const bf16x8 v2 = *(const bf16x8*)&h2[((size_t)4           * B_ + b) * H2_ + o0];
    const bf16x8 v3 = *(const bf16x8*)&h2[((size_t)5           * B_ + b) * H2_ + o0];
    float r[8];
#pragma unroll
    for (int i = 0; i < 8; ++i)
        r[i] = gv.x * (float)v0[i] + gv.y * (float)v1[i]
             + gv.z * (float)v2[i] + gv.w * (float)v3[i];
    float4* op = (float4*)&out[tb * H2_ + o0];
    op[0] = make_float4(r[0], r[1], r[2], r[3]);
    op[1] = make_float4(r[4], r[5], r[6], r[7]);
}

// ---------------------------------------------------------------------------
extern "C" void kernel_launch(void* const* d_in, const int* in_sizes, int n_in,
                              void* d_out, int out_size, void* d_ws, size_t ws_size,
                              hipStream_t stream)
{
    const float* x   = (const float*)d_in[0];
    const float* We1 = (const float*)d_in[1];
    const float* be1 = (const float*)d_in[2];
    const float* We2 = (const float*)d_in[3];
    const float* be2 = (const float*)d_in[4];
    const float* Wg1 = (const float*)d_in[5];
    const float* bg1 = (const float*)d_in[6];
    const float* Wgs = (const float*)d_in[7];
    float* out = (float*)d_out;

    char* ws = (char*)d_ws;
    bf16_t* x_bf = (bf16_t*)ws;  ws += (size_t)B_ * D_ * 2;
    bf16_t* w1t  = (bf16_t*)ws;  ws += (size_t)E_ * H1_ * D_ * 2;
    bf16_t* w2t  = (bf16_t*)ws;  ws += (size_t)E_ * H2_ * H1_ * 2;
    bf16_t* wgt  = (bf16_t*)ws;  ws += (size_t)T_ * G_ * D_ * 2;
    bf16_t* h1   = (bf16_t*)ws;  ws += (size_t)E_ * B_ * H1_ * 2;
    bf16_t* h2   = (bf16_t*)ws;  ws += (size_t)E_ * B_ * H2_ * 2;
    bf16_t* gbuf = (bf16_t*)ws;  ws += (size_t)T_ * B_ * G_ * 2;
    float*  gate = (float*)ws;   ws += (size_t)T_ * B_ * EC_ * 4;

    // 1) casts / transposes
    cast_x_kernel<<<(B_ * D_ / 8) / 256, 256, 0, stream>>>(x, x_bf, B_ * D_ / 8);
    dim3 tb(32, 8);
    transpose_cast_kernel<<<dim3(H1_ / 32, D_ / 32, E_),  tb, 0, stream>>>(We1, w1t, D_,  H1_);
    transpose_cast_kernel<<<dim3(H2_ / 32, H1_ / 32, E_), tb, 0, stream>>>(We2, w2t, H1_, H2_);
    transpose_cast_kernel<<<dim3(G_ / 32, D_ / 32, T_),   tb, 0, stream>>>(Wg1, wgt, D_,  G_);

    // 2) expert MLP GEMMs on the 256^2 phase-split kernel
    gemm256_bt_bias_relu<<<dim3(H1_ / 256, B_ / 256, E_), 512, 0, stream>>>(
        x_bf, w1t, be1, h1, B_, H1_, D_, 0LL);
    gemm256_bt_bias_relu<<<dim3(H2_ / 256, B_ / 256, E_), 512, 0, stream>>>(
        h1, w2t, be2, h2, B_, H2_, H1_, (long long)B_ * H1_);

    // gate GEMM keeps the 128^2 kernel (better occupancy at N=512, T=2)
    gemm_bt_bias_relu<<<dim3(G_ / 128, B_ / 128, T_), 256, 0, stream>>>(
        x_bf, wgt, bg1, gbuf, B_, G_, D_, 0LL);

    // 3) gate softmax + final combine
    gate_kernel<<<(T_ * B_) / 4, 256, 0, stream>>>(gbuf, Wgs, gate);
    combine_kernel<<<((size_t)T_ * B_ * H2_ / 8) / 256, 256, 0, stream>>>(h2, gate, out);
}

// Round 3
// 408.269 us; speedup vs baseline: 1.2100x; 1.0273x over previous
//
#include <hip/hip_runtime.h>
#include <hip/hip_bf16.h>
#include <cstdint>
#include <cstddef>

#define B_   8192
#define D_   2048
#define H1_  1024
#define H2_  512
#define G_   512
#define T_   2
#define E_   6
#define EC_  4

typedef __bf16 bf16_t;
typedef __attribute__((ext_vector_type(8))) __bf16 bf16x8;
typedef __attribute__((ext_vector_type(4))) float f32x4;

// ---------------------------------------------------------------------------
// async global->LDS, 16B per lane. LDS dest is wave-uniform base + lane*16.
// ---------------------------------------------------------------------------
__device__ __forceinline__ void gload_lds16(const bf16_t* g, bf16_t* l) {
    __builtin_amdgcn_global_load_lds(
        (const __attribute__((address_space(1))) bf16_t*)g,
        (__attribute__((address_space(3))) bf16_t*)l,
        16, 0, 0);
}

// ---------------------------------------------------------------------------
// cast x (fp32) -> bf16, 8 elems/thread
// ---------------------------------------------------------------------------
__global__ __launch_bounds__(256) void cast_x_kernel(
    const float* __restrict__ src, bf16_t* __restrict__ dst, int n8)
{
    int i = blockIdx.x * blockDim.x + threadIdx.x;
    if (i >= n8) return;
    const float4* s = (const float4*)src + (size_t)i * 2;
    float4 a = s[0], b = s[1];
    bf16x8 o;
    o[0] = (bf16_t)a.x; o[1] = (bf16_t)a.y; o[2] = (bf16_t)a.z; o[3] = (bf16_t)a.w;
    o[4] = (bf16_t)b.x; o[5] = (bf16_t)b.y; o[6] = (bf16_t)b.z; o[7] = (bf16_t)b.w;
    *(bf16x8*)(dst + (size_t)i * 8) = o;
}

// ---------------------------------------------------------------------------
// transpose + cast: src (batch, R, C) fp32 -> dst (batch, C, R) bf16
// ---------------------------------------------------------------------------
__global__ __launch_bounds__(256) void transpose_cast_kernel(
    const float* __restrict__ src, bf16_t* __restrict__ dst, int R, int C)
{
    __shared__ float tile[32][33];
    int bz = blockIdx.z;
    src += (size_t)bz * R * C;
    dst += (size_t)bz * R * C;
    int c0 = blockIdx.x * 32, r0 = blockIdx.y * 32;
    int tx = threadIdx.x, ty = threadIdx.y;
#pragma unroll
    for (int i = 0; i < 32; i += 8)
        tile[ty + i][tx] = src[(size_t)(r0 + ty + i) * C + (c0 + tx)];
    __syncthreads();
#pragma unroll
    for (int i = 0; i < 32; i += 8)
        dst[(size_t)(c0 + ty + i) * R + (r0 + tx)] = (bf16_t)tile[tx][ty + i];
}

// ---------------------------------------------------------------------------
// 256x256-tile, BK=64, 8-phase m201-style GEMM:
//   C = relu(A(M,K) * Bt(N,K)^T + bias), bf16 in/out, fp32 MFMA accumulate.
// 8 waves (2M x 4N), per-wave 128x64 output. 2 LDS dbuf (128 KB total).
// Per iteration: 2 K-tiles, 8 phases; phase = quadrant(2 m-frags) x K=64.
// B-frags read once per K-tile (qm==0), held 4 phases. One half-tile staged
// per phase; counted vmcnt(4) only at phases 4/8 (never 0 in steady state).
// XOR swizzle (chunk ^= row&7, 16B chunks) on BOTH stage-source and ds_read.
// Requires: M%256==0, N%256==0, K%128==0, K/64>=4, gridX*gridY%8==0.
// ---------------------------------------------------------------------------
__global__ __launch_bounds__(512, 2) void gemm256k64_bt_bias_relu(
    const bf16_t* __restrict__ A, const bf16_t* __restrict__ Bt,
    const float* __restrict__ bias, bf16_t* __restrict__ C,
    int M, int N, int K, long long strideA)
{
    const int e = blockIdx.z;
    A    += (size_t)e * (size_t)strideA;
    Bt   += (size_t)e * (size_t)N * (size_t)K;
    bias += (size_t)e * (size_t)N;
    C    += (size_t)e * (size_t)M * (size_t)N;

    // T1: XCD swizzle within this z-slice (nwg % 8 == 0 guaranteed by launch)
    const int gx  = gridDim.x;
    const int nwg = gx * gridDim.y;
    const int lin = blockIdx.y * gx + blockIdx.x;
    const int swz = (lin & 7) * (nwg >> 3) + (lin >> 3);
    const int bx  = swz % gx;
    const int by  = swz / gx;
    const int row0 = by * 256;
    const int col0 = bx * 256;

    __shared__ bf16_t lsA[2][16384];   // [dbuf][256 rows x 64], 64 KB
    __shared__ bf16_t lsB[2][16384];   // 64 KB

    const int tid  = threadIdx.x;
    const int lane = tid & 63;
    const int wave = tid >> 6;        // 0..7
    const int wr   = wave >> 2;       // 0..1 : M-half (128 rows)
    const int wc   = wave & 3;        // 0..3 : N-quarter (64 cols)

    // ---- staging geometry: one half-tile = 128 rows x 8 chunks(16B) --------
    // linear LDS slot idx = l*512 + tid sources logical chunk c = phys ^ (row&7)
    size_t offG[2];
    int    ldsOff[2];
#pragma unroll
    for (int l = 0; l < 2; ++l) {
        int idx = l * 512 + tid;
        int r   = idx >> 3;                       // row within half, 0..127
        int c   = (idx & 7) ^ (r & 7);            // logical chunk
        offG[l]   = (size_t)r * (size_t)K + (size_t)(c * 8);
        ldsOff[l] = l * 4096 + wave * 512;        // elements, wave-uniform
    }
    const bf16_t* gA = A  + (size_t)row0 * (size_t)K;
    const bf16_t* gB = Bt + (size_t)col0 * (size_t)K;
    const size_t halfStride = (size_t)128 * (size_t)K;

    // ---- fragment read addressing (elements), same XOR involution ----------
    // row&7 == lane&7 (row bases are multiples of 16)
    const int rbA = (wr * 128 + (lane & 15)) * 64;
    const int rbB = (wc * 64  + (lane & 15)) * 64;
    int xc[2];
#pragma unroll
    for (int ks = 0; ks < 2; ++ks)
        xc[ks] = (ks * 32 + ((lane >> 4) * 8)) ^ ((lane & 7) << 3);

    f32x4 acc[8][4];
#pragma unroll
    for (int m = 0; m < 8; ++m)
#pragma unroll
        for (int n = 0; n < 4; ++n)
            acc[m][n] = (f32x4){0.f, 0.f, 0.f, 0.f};

    const int nt    = K >> 6;         // K-tiles of 64
    const int niter = nt >> 1;        // 2 K-tiles per iteration

#define STAGE_A(dst, kt, h) do {                                              \
    _Pragma("unroll")                                                         \
    for (int l_ = 0; l_ < 2; ++l_)                                            \
        gload_lds16(gA + (size_t)((kt) * 64) + (size_t)(h) * halfStride       \
                       + offG[l_],                                            \
                    &lsA[dst][(h) * 8192 + ldsOff[l_]]);                      \
} while (0)

#define STAGE_B(dst, kt, h) do {                                              \
    _Pragma("unroll")                                                         \
    for (int l_ = 0; l_ < 2; ++l_)                                            \
        gload_lds16(gB + (size_t)((kt) * 64) + (size_t)(h) * halfStride       \
                       + offG[l_],                                            \
                    &lsB[dst][(h) * 8192 + ldsOff[l_]]);                      \
} while (0)

// phase: quadrant qm of dbuf d. reads A (4x b128; +B 8x b128 when qm==0),
// stages one half-tile (STMT), then barrier / lgkm(0) / MFMA x16 / ENDW / bar.
#define PHASE(d, qm, STMT, ENDW) do {                                         \
    bf16x8 af00, af01, af10, af11;                                            \
    af00 = *(const bf16x8*)&lsA[d][rbA + (2*(qm)+0) * 1024 + xc[0]];          \
    af01 = *(const bf16x8*)&lsA[d][rbA + (2*(qm)+0) * 1024 + xc[1]];          \
    af10 = *(const bf16x8*)&lsA[d][rbA + (2*(qm)+1) * 1024 + xc[0]];          \
    af11 = *(const bf16x8*)&lsA[d][rbA + (2*(qm)+1) * 1024 + xc[1]];          \
    if ((qm) == 0) {                                                          \
        _Pragma("unroll")                                                     \
        for (int n_ = 0; n_ < 4; ++n_) {                                      \
            bfr[n_][0] = *(const bf16x8*)&lsB[d][rbB + n_ * 1024 + xc[0]];    \
            bfr[n_][1] = *(const bf16x8*)&lsB[d][rbB + n_ * 1024 + xc[1]];    \
        }                                                                     \
    }                                                                         \
    STMT;                                                                     \
    __builtin_amdgcn_sched_barrier(0);                                        \
    __builtin_amdgcn_s_barrier();                                             \
    asm volatile("s_waitcnt lgkmcnt(0)" ::: "memory");                        \
    __builtin_amdgcn_sched_barrier(0);                                        \
    __builtin_amdgcn_s_setprio(1);                                            \
    _Pragma("unroll")                                                         \
    for (int n_ = 0; n_ < 4; ++n_) {                                          \
        acc[2*(qm)+0][n_] = __builtin_amdgcn_mfma_f32_16x16x32_bf16(          \
                                af00, bfr[n_][0], acc[2*(qm)+0][n_], 0,0,0);  \
        acc[2*(qm)+0][n_] = __builtin_amdgcn_mfma_f32_16x16x32_bf16(          \
                                af01, bfr[n_][1], acc[2*(qm)+0][n_], 0,0,0);  \
        acc[2*(qm)+1][n_] = __builtin_amdgcn_mfma_f32_16x16x32_bf16(          \
                                af10, bfr[n_][0], acc[2*(qm)+1][n_], 0,0,0);  \
        acc[2*(qm)+1][n_] = __builtin_amdgcn_mfma_f32_16x16x32_bf16(          \
                                af11, bfr[n_][1], acc[2*(qm)+1][n_], 0,0,0);  \
    }                                                                         \
    __builtin_amdgcn_s_setprio(0);                                            \
    ENDW;                                                                     \
    __builtin_amdgcn_sched_barrier(0);                                        \
    __builtin_amdgcn_s_barrier();                                             \
} while (0)

    // ---- prologue: B(0)h0,h1  A(0)h0,h1  B(1)h0,h1 (issue order matters) ---
    STAGE_B(0, 0, 0); STAGE_B(0, 0, 1);
    STAGE_A(0, 0, 0); STAGE_A(0, 0, 1);
    STAGE_B(1, 1, 0); STAGE_B(1, 1, 1);
    asm volatile("s_waitcnt vmcnt(4)" ::: "memory");   // B(0),A(0) complete
    __builtin_amdgcn_sched_barrier(0);
    __builtin_amdgcn_s_barrier();

    // ---- main loop: iter i computes kt0=2i (buf0, p0-3), kt1=2i+1 (buf1) ---
    // stage slots: p0:A(kt1)h0  p1:A(kt1)h1  p2:B(kt0+2)h0  p3:B(kt0+2)h1
    //              p4:A(kt0+2)h0 p5:A(kt0+2)h1 p6:B(kt0+3)h0 p7:B(kt0+3)h1
    // vmcnt(4) at end-p3 (drains A(kt1),B(kt1)) and end-p7 (drains tile kt0+2)
    for (int i = 0; i < niter; ++i) {
        const int kt0 = 2 * i, kt1 = 2 * i + 1;
        const bool stg = (i + 1 < niter);
        bf16x8 bfr[4][2];

        PHASE(0, 0, { STAGE_A(1, kt1, 0); }, {});
        PHASE(0, 1, { STAGE_A(1, kt1, 1); }, {});
        PHASE(0, 2, { if (stg) STAGE_B(0, kt0 + 2, 0); }, {});
        PHASE(0, 3, { if (stg) STAGE_B(0, kt0 + 2, 1); },
              { if (stg) { asm volatile("s_waitcnt vmcnt(4)" ::: "memory"); }
                else     { asm volatile("s_waitcnt vmcnt(0)" ::: "memory"); } });
        PHASE(1, 0, { if (stg) STAGE_A(0, kt0 + 2, 0); }, {});
        PHASE(1, 1, { if (stg) STAGE_A(0, kt0 + 2, 1); }, {});
        PHASE(1, 2, { if (stg) STAGE_B(1, kt0 + 3, 0); }, {});
        PHASE(1, 3, { if (stg) STAGE_B(1, kt0 + 3, 1); },
              { if (stg) { asm volatile("s_waitcnt vmcnt(4)" ::: "memory"); } });
    }
#undef PHASE
#undef STAGE_A
#undef STAGE_B

    // ---- epilogue: C/D layout col = lane&15, row = (lane>>4)*4 + j ----------
    const int crb = row0 + wr * 128 + ((lane >> 4) << 2);
    const int ccb = col0 + wc * 64  + (lane & 15);
#pragma unroll
    for (int n = 0; n < 4; ++n) {
        const int cc = ccb + n * 16;
        const float bv = bias[cc];
#pragma unroll
        for (int m = 0; m < 8; ++m) {
            const int rb = crb + m * 16;
#pragma unroll
            for (int j = 0; j < 4; ++j) {
                float v = acc[m][n][j] + bv;
                v = v > 0.f ? v : 0.f;
                C[(size_t)(rb + j) * N + cc] = (bf16_t)v;
            }
        }
    }
}

// ---------------------------------------------------------------------------
// m97-structure 128x128 GEMM (round-1 proven) — used for the gate GEMM.
// ---------------------------------------------------------------------------
__global__ __launch_bounds__(256) void gemm_bt_bias_relu(
    const bf16_t* __restrict__ A, const bf16_t* __restrict__ Bt,
    const float* __restrict__ bias, bf16_t* __restrict__ C,
    int M, int N, int K, long long strideA)
{
    const int e = blockIdx.z;
    A    += (size_t)e * (size_t)strideA;
    Bt   += (size_t)e * (size_t)N * (size_t)K;
    bias += (size_t)e * (size_t)N;
    C    += (size_t)e * (size_t)M * (size_t)N;

    __shared__ bf16_t lsA[128 * 32];
    __shared__ bf16_t lsB[128 * 32];

    const int tid  = threadIdx.x;
    const int lane = tid & 63;
    const int wave = tid >> 6;
    const int wr   = wave >> 1;
    const int wc   = wave & 1;
    const int row0 = blockIdx.y * 128;
    const int col0 = blockIdx.x * 128;

    int sRow[2], sCol[2];
#pragma unroll
    for (int r = 0; r < 2; ++r) {
        int s = (r * 4 + wave) * 512 + lane * 8;
        sRow[r] = s >> 5;
        sCol[r] = s & 31;
    }

    f32x4 acc[4][4];
#pragma unroll
    for (int m = 0; m < 4; ++m)
#pragma unroll
        for (int n = 0; n < 4; ++n)
            acc[m][n] = (f32x4){0.f, 0.f, 0.f, 0.f};

    const int aRowBase = wr * 64 + (lane & 15);
    const int bRowBase = wc * 64 + (lane & 15);
    const int kcol     = (lane >> 4) * 8;

    for (int k0 = 0; k0 < K; k0 += 32) {
#pragma unroll
        for (int r = 0; r < 2; ++r) {
            gload_lds16(A  + (size_t)(row0 + sRow[r]) * K + (k0 + sCol[r]),
                        lsA + (r * 4 + wave) * 512);
            gload_lds16(Bt + (size_t)(col0 + sRow[r]) * K + (k0 + sCol[r]),
                        lsB + (r * 4 + wave) * 512);
        }
        __syncthreads();

        bf16x8 af[4], bfr[4];
#pragma unroll
        for (int m = 0; m < 4; ++m)
            af[m] = *(const bf16x8*)&lsA[(aRowBase + m * 16) * 32 + kcol];
#pragma unroll
        for (int n = 0; n < 4; ++n)
            bfr[n] = *(const bf16x8*)&lsB[(bRowBase + n * 16) * 32 + kcol];

#pragma unroll
        for (int m = 0; m < 4; ++m)
#pragma unroll
            for (int n = 0; n < 4; ++n)
                acc[m][n] = __builtin_amdgcn_mfma_f32_16x16x32_bf16(
                                af[m], bfr[n], acc[m][n], 0, 0, 0);
        __syncthreads();
    }

    const int crow = row0 + wr * 64 + ((lane >> 4) << 2);
    const int ccol = col0 + wc * 64 + (lane & 15);
#pragma unroll
    for (int n = 0; n < 4; ++n) {
        int cc = ccol + n * 16;
        float bv = bias[cc];
#pragma unroll
        for (int m = 0; m < 4; ++m) {
            int rb = crow + m * 16;
#pragma unroll
            for (int j = 0; j < 4; ++j) {
                float v = acc[m][n][j] + bv;
                v = v > 0.f ? v : 0.f;
                C[(size_t)(rb + j) * N + cc] = (bf16_t)v;
            }
        }
    }
}

// ---------------------------------------------------------------------------
// gate: logits[t,b,e] = sum_g g[t,b,g] * Wgs[t,g,e]; softmax over e (EC=4).
// ---------------------------------------------------------------------------
__global__ __launch_bounds__(256) void gate_kernel(
    const bf16_t* __restrict__ g, const float* __restrict__ Wgs,
    float* __restrict__ gate)
{
    int wid  = blockIdx.x * 4 + (threadIdx.x >> 6);
    int lane = threadIdx.x & 63;
    int t = wid >> 13;
    const bf16_t* grow = g + (size_t)wid * G_;
    bf16x8 gv = *(const bf16x8*)&grow[lane * 8];
    const float* W = Wgs + (size_t)t * G_ * EC_;
    float a0 = 0.f, a1 = 0.f, a2 = 0.f, a3 = 0.f;
#pragma unroll
    for (int i = 0; i < 8; ++i) {
        float gvf = (float)gv[i];
        const float4 w = *(const float4*)&W[(size_t)(lane * 8 + i) * 4];
        a0 += gvf * w.x; a1 += gvf * w.y; a2 += gvf * w.z; a3 += gvf * w.w;
    }
#pragma unroll
    for (int off = 32; off; off >>= 1) {
        a0 += __shfl_xor(a0, off);
        a1 += __shfl_xor(a1, off);
        a2 += __shfl_xor(a2, off);
        a3 += __shfl_xor(a3, off);
    }
    if (lane == 0) {
        float m  = fmaxf(fmaxf(a0, a1), fmaxf(a2, a3));
        float e0 = expf(a0 - m), e1 = expf(a1 - m), e2 = expf(a2 - m), e3 = expf(a3 - m);
        float inv = 1.f / (e0 + e1 + e2 + e3);
        *(float4*)&gate[(size_t)wid * 4] = make_float4(e0 * inv, e1 * inv, e2 * inv, e3 * inv);
    }
}

// ---------------------------------------------------------------------------
// combine: out[t,b,o] = sum_j gate[t,b,j] * h2[IDX[t][j], b, o]
// ---------------------------------------------------------------------------
__global__ __launch_bounds__(256) void combine_kernel(
    const bf16_t* __restrict__ h2, const float* __restrict__ gate,
    float* __restrict__ out)
{
    size_t idx = (size_t)blockIdx.x * 256 + threadIdx.x;
    size_t tb  = idx >> 6;
    int    o0  = (int)(idx & 63) * 8;
    int    t   = (int)(tb >> 13);
    size_t b   = tb & (size_t)(B_ - 1);
    const float4 gv = *(const float4*)&gate[tb * 4];
    const bf16x8 v0 = *(const bf16x8*)&h2[((size_t)(2 * t)     * B_ + b) * H2_ + o0];
    const bf16x8 v1 = *(const bf16x8*)&h2[((size_t)(2 * t + 1) * B_ + b) * H2_ + o0];
    const bf16x8 v2 = *(const bf16x8*)&h2[((size_t)4           * B_ + b) * H2_ + o0];
    const bf16x8 v3 = *(const bf16x8*)&h2[((size_t)5           * B_ + b) * H2_ + o0];
    float r[8];
#pragma unroll
    for (int i = 0; i < 8; ++i)
        r[i] = gv.x * (float)v0[i] + gv.y * (float)v1[i]
             + gv.z * (float)v2[i] + gv.w * (float)v3[i];
    float4* op = (float4*)&out[tb * H2_ + o0];
    op[0] = make_float4(r[0], r[1], r[2], r[3]);
    op[1] = make_float4(r[4], r[5], r[6], r[7]);
}

// ---------------------------------------------------------------------------
extern "C" void kernel_launch(void* const* d_in, const int* in_sizes, int n_in,
                              void* d_out, int out_size, void* d_ws, size_t ws_size,
                              hipStream_t stream)
{
    const float* x   = (const float*)d_in[0];
    const float* We1 = (const float*)d_in[1];
    const float* be1 = (const float*)d_in[2];
    const float* We2 = (const float*)d_in[3];
    const float* be2 = (const float*)d_in[4];
    const float* Wg1 = (const float*)d_in[5];
    const float* bg1 = (const float*)d_in[6];
    const float* Wgs = (const float*)d_in[7];
    float* out = (float*)d_out;

    char* ws = (char*)d_ws;
    bf16_t* x_bf = (bf16_t*)ws;  ws += (size_t)B_ * D_ * 2;
    bf16_t* w1t  = (bf16_t*)ws;  ws += (size_t)E_ * H1_ * D_ * 2;
    bf16_t* w2t  = (bf16_t*)ws;  ws += (size_t)E_ * H2_ * H1_ * 2;
    bf16_t* wgt  = (bf16_t*)ws;  ws += (size_t)T_ * G_ * D_ * 2;
    bf16_t* h1   = (bf16_t*)ws;  ws += (size_t)E_ * B_ * H1_ * 2;
    bf16_t* h2   = (bf16_t*)ws;  ws += (size_t)E_ * B_ * H2_ * 2;
    bf16_t* gbuf = (bf16_t*)ws;  ws += (size_t)T_ * B_ * G_ * 2;
    float*  gate = (float*)ws;   ws += (size_t)T_ * B_ * EC_ * 4;

    // 1) casts / transposes
    cast_x_kernel<<<(B_ * D_ / 8) / 256, 256, 0, stream>>>(x, x_bf, B_ * D_ / 8);
    dim3 tb(32, 8);
    transpose_cast_kernel<<<dim3(H1_ / 32, D_ / 32, E_),  tb, 0, stream>>>(We1, w1t, D_,  H1_);
    transpose_cast_kernel<<<dim3(H2_ / 32, H1_ / 32, E_), tb, 0, stream>>>(We2, w2t, H1_, H2_);
    transpose_cast_kernel<<<dim3(G_ / 32, D_ / 32, T_),   tb, 0, stream>>>(Wg1, wgt, D_,  G_);

    // 2) expert MLP GEMMs on the 8-phase 256^2 kernel
    gemm256k64_bt_bias_relu<<<dim3(H1_ / 256, B_ / 256, E_), 512, 0, stream>>>(
        x_bf, w1t, be1, h1, B_, H1_, D_, 0LL);
    gemm256k64_bt_bias_relu<<<dim3(H2_ / 256, B_ / 256, E_), 512, 0, stream>>>(
        h1, w2t, be2, h2, B_, H2_, H1_, (long long)B_ * H1_);

    // gate GEMM keeps the 128^2 kernel (N=512, T=2: occupancy)
    gemm_bt_bias_relu<<<dim3(G_ / 128, B_ / 128, T_), 256, 0, stream>>>(
        x_bf, wgt, bg1, gbuf, B_, G_, D_, 0LL);

    // 3) gate softmax + final combine
    gate_kernel<<<(T_ * B_) / 4, 256, 0, stream>>>(gbuf, Wgs, gate);
    combine_kernel<<<((size_t)T_ * B_ * H2_ / 8) / 256, 256, 0, stream>>>(h2, gate, out);
}

// Round 4
// 381.724 us; speedup vs baseline: 1.2941x; 1.0695x over previous
//
#include <hip/hip_runtime.h>
#include <hip/hip_bf16.h>
#include <cstdint>
#include <cstddef>

#define B_   8192
#define D_   2048
#define H1_  1024
#define H2_  512
#define G_   512
#define T_   2
#define E_   6
#define EC_  4

typedef __bf16 bf16_t;
typedef __attribute__((ext_vector_type(8))) __bf16 bf16x8;
typedef __attribute__((ext_vector_type(4))) float f32x4;

// ---------------------------------------------------------------------------
// async global->LDS, 16B per lane. LDS dest is wave-uniform base + lane*16.
// ---------------------------------------------------------------------------
__device__ __forceinline__ void gload_lds16(const bf16_t* g, bf16_t* l) {
    __builtin_amdgcn_global_load_lds(
        (const __attribute__((address_space(1))) bf16_t*)g,
        (__attribute__((address_space(3))) bf16_t*)l,
        16, 0, 0);
}

// ---------------------------------------------------------------------------
// cast x (fp32) -> bf16, 8 elems/thread
// ---------------------------------------------------------------------------
__global__ __launch_bounds__(256) void cast_x_kernel(
    const float* __restrict__ src, bf16_t* __restrict__ dst, int n8)
{
    int i = blockIdx.x * blockDim.x + threadIdx.x;
    if (i >= n8) return;
    const float4* s = (const float4*)src + (size_t)i * 2;
    float4 a = s[0], b = s[1];
    bf16x8 o;
    o[0] = (bf16_t)a.x; o[1] = (bf16_t)a.y; o[2] = (bf16_t)a.z; o[3] = (bf16_t)a.w;
    o[4] = (bf16_t)b.x; o[5] = (bf16_t)b.y; o[6] = (bf16_t)b.z; o[7] = (bf16_t)b.w;
    *(bf16x8*)(dst + (size_t)i * 8) = o;
}

// ---------------------------------------------------------------------------
// transpose + cast: src (batch, R, C) fp32 -> dst (batch, C, R) bf16
// ---------------------------------------------------------------------------
__global__ __launch_bounds__(256) void transpose_cast_kernel(
    const float* __restrict__ src, bf16_t* __restrict__ dst, int R, int C)
{
    __shared__ float tile[32][33];
    int bz = blockIdx.z;
    src += (size_t)bz * R * C;
    dst += (size_t)bz * R * C;
    int c0 = blockIdx.x * 32, r0 = blockIdx.y * 32;
    int tx = threadIdx.x, ty = threadIdx.y;
#pragma unroll
    for (int i = 0; i < 32; i += 8)
        tile[ty + i][tx] = src[(size_t)(r0 + ty + i) * C + (c0 + tx)];
    __syncthreads();
#pragma unroll
    for (int i = 0; i < 32; i += 8)
        dst[(size_t)(c0 + ty + i) * R + (r0 + tx)] = (bf16_t)tile[tx][ty + i];
}

// ---------------------------------------------------------------------------
// 128x256-tile GEMM, 2 blocks/CU: C = relu(A(M,K)*Bt(N,K)^T + bias), bf16.
// 8 waves (2M x 4N), per-wave 64x64 (acc = 64 VGPR). BK=32.
// 3-buffer LDS rotation (72 KB) -> 2 blocks/CU at <=128 VGPR: cross-block
// TLP fills each block's barrier/LDS segments (m114/m97 mechanism).
// Counted vmcnt(6) steady state (2 tiles in flight), drains only in tail.
// XOR swizzle chunk ^= (row>>1)&3 on BOTH stage-source and ds_read (rule 21):
// full-wave b128 read touches all 32 banks exactly 2x per quarter (free).
// Requires: M%128==0, N%256==0, K%32==0, K/32>=4, gridX*gridY%8==0.
// ---------------------------------------------------------------------------
__global__ __launch_bounds__(512, 4) void gemm_bn256_bias_relu(
    const bf16_t* __restrict__ A, const bf16_t* __restrict__ Bt,
    const float* __restrict__ bias, bf16_t* __restrict__ C,
    int M, int N, int K, long long strideA)
{
    const int e = blockIdx.z;
    A    += (size_t)e * (size_t)strideA;
    Bt   += (size_t)e * (size_t)N * (size_t)K;
    bias += (size_t)e * (size_t)N;
    C    += (size_t)e * (size_t)M * (size_t)N;

    // T1: XCD swizzle within this z-slice (nwg % 8 == 0 by launch contract)
    const int gx  = gridDim.x;
    const int nwg = gx * gridDim.y;
    const int lin = blockIdx.y * gx + blockIdx.x;
    const int swz = (lin & 7) * (nwg >> 3) + (lin >> 3);
    const int row0 = (swz / gx) * 128;
    const int col0 = (swz % gx) * 256;

    __shared__ bf16_t lsA[3][128 * 32];   // 3 x 8 KB
    __shared__ bf16_t lsB[3][256 * 32];   // 3 x 16 KB   -> 72 KB total

    const int tid  = threadIdx.x;
    const int lane = tid & 63;
    const int wave = tid >> 6;        // 0..7
    const int wr   = wave >> 2;       // 0..1 : 64-row half
    const int wc   = wave & 3;        // 0..3 : 64-col quarter

    // ---- staging source offsets (global, elements) --------------------------
    // A: 1 load/thread (slot=tid); B: 2 loads (slot=l*512+tid).
    // slot -> row=slot>>2, phys chunk=slot&3, logical chunk = pc ^ ((row>>1)&3)
    size_t offA, offB0, offB1;
    {
        int rA = tid >> 2, pA = tid & 3;
        offA = (size_t)rA * (size_t)K + (size_t)(((pA ^ (rA >> 1)) & 3) * 8);
        int r0_ = tid >> 2, p0_ = tid & 3;                 // slot = tid
        offB0 = (size_t)r0_ * (size_t)K + (size_t)(((p0_ ^ (r0_ >> 1)) & 3) * 8);
        int r1_ = (512 + tid) >> 2, p1_ = tid & 3;         // slot = 512 + tid
        offB1 = (size_t)r1_ * (size_t)K + (size_t)(((p1_ ^ (r1_ >> 1)) & 3) * 8);
    }
    const int ldsA_off = wave * 512;            // elements, wave-uniform
    const int ldsB0off = wave * 512;
    const int ldsB1off = 4096 + wave * 512;

    const bf16_t* gA = A  + (size_t)row0 * (size_t)K;
    const bf16_t* gB = Bt + (size_t)col0 * (size_t)K;

    // ---- fragment read offsets (elements), same XOR involution --------------
    const int xch  = ((lane >> 4) ^ ((lane >> 1) & 3)) << 3;
    const int aoff = (wr * 64 + (lane & 15)) * 32 + xch;
    const int boff = (wc * 64 + (lane & 15)) * 32 + xch;

    f32x4 acc[4][4];
#pragma unroll
    for (int m = 0; m < 4; ++m)
#pragma unroll
        for (int n = 0; n < 4; ++n)
            acc[m][n] = (f32x4){0.f, 0.f, 0.f, 0.f};

    const int nt = K >> 5;            // K-tiles of 32, nt >= 4

#define STAGE(t_, c_) do {                                                    \
    const size_t kk_ = (size_t)(t_) * 32;                                     \
    gload_lds16(gA + kk_ + offA,  &lsA[c_][ldsA_off]);                        \
    gload_lds16(gB + kk_ + offB0, &lsB[c_][ldsB0off]);                        \
    gload_lds16(gB + kk_ + offB1, &lsB[c_][ldsB1off]);                        \
} while (0)

    // ---- prologue: stage tiles 0,1,2 ---------------------------------------
    STAGE(0, 0); STAGE(1, 1); STAGE(2, 2);
    asm volatile("s_waitcnt vmcnt(6)" ::: "memory");   // tile 0 complete
    __builtin_amdgcn_s_barrier();
    __builtin_amdgcn_sched_barrier(0);

    int c = 0;
    for (int t = 0; t < nt; ++t) {
        bf16x8 a[4], b[4];
#pragma unroll
        for (int m = 0; m < 4; ++m)
            a[m] = *(const bf16x8*)&lsA[c][aoff + m * 512];
#pragma unroll
        for (int n = 0; n < 4; ++n)
            b[n] = *(const bf16x8*)&lsB[c][boff + n * 512];
        // own frags in regs before the barrier releases this buffer
        asm volatile("s_waitcnt lgkmcnt(0)" ::: "memory");
        __builtin_amdgcn_sched_barrier(0);
        __builtin_amdgcn_s_barrier();     // all waves done reading buf c
        __builtin_amdgcn_sched_barrier(0);
        if (t + 3 < nt) STAGE(t + 3, c);  // overwrite freed buffer
        __builtin_amdgcn_sched_barrier(0);
        __builtin_amdgcn_s_setprio(1);
#pragma unroll
        for (int m = 0; m < 4; ++m)
#pragma unroll
            for (int n = 0; n < 4; ++n)
                acc[m][n] = __builtin_amdgcn_mfma_f32_16x16x32_bf16(
                                a[m], b[n], acc[m][n], 0, 0, 0);
        __builtin_amdgcn_s_setprio(0);
        __builtin_amdgcn_sched_barrier(0);
        // counted wait: steady state leaves tiles t+2,t+3 (6 loads) in flight
        if (t + 3 < nt) { asm volatile("s_waitcnt vmcnt(6)" ::: "memory"); }
        else            { asm volatile("s_waitcnt vmcnt(0)" ::: "memory"); }
        __builtin_amdgcn_sched_barrier(0);
        __builtin_amdgcn_s_barrier();     // tile t+1 visible to all waves
        __builtin_amdgcn_sched_barrier(0);
        c = (c == 2) ? 0 : c + 1;
    }
#undef STAGE

    // ---- epilogue: C/D layout col = lane&15, row = (lane>>4)*4 + j ----------
    const int crb = row0 + wr * 64 + ((lane >> 4) << 2);
    const int ccb = col0 + wc * 64 + (lane & 15);
#pragma unroll
    for (int n = 0; n < 4; ++n) {
        const int cc = ccb + n * 16;
        const float bv = bias[cc];
#pragma unroll
        for (int m = 0; m < 4; ++m) {
            const int rb = crb + m * 16;
#pragma unroll
            for (int j = 0; j < 4; ++j) {
                float v = acc[m][n][j] + bv;
                v = v > 0.f ? v : 0.f;
                C[(size_t)(rb + j) * N + cc] = (bf16_t)v;
            }
        }
    }
}

// ---------------------------------------------------------------------------
// gate: logits[t,b,e] = sum_g g[t,b,g] * Wgs[t,g,e]; softmax over e (EC=4).
// g now lives in h1 slice 6: row (t,b) at h1[(6*B + b)*1024 + t*512 ..].
// ---------------------------------------------------------------------------
__global__ __launch_bounds__(256) void gate_kernel(
    const bf16_t* __restrict__ h1, const float* __restrict__ Wgs,
    float* __restrict__ gate)
{
    int wid  = blockIdx.x * 4 + (threadIdx.x >> 6);   // t*B + b
    int lane = threadIdx.x & 63;
    int t = wid >> 13;                                // B_ = 8192
    int b = wid & (B_ - 1);
    const bf16_t* grow = h1 + ((size_t)(6 * B_) + b) * 1024 + t * G_;
    bf16x8 gv = *(const bf16x8*)&grow[lane * 8];
    const float* W = Wgs + (size_t)t * G_ * EC_;
    float a0 = 0.f, a1 = 0.f, a2 = 0.f, a3 = 0.f;
#pragma unroll
    for (int i = 0; i < 8; ++i) {
        float gvf = (float)gv[i];
        const float4 w = *(const float4*)&W[(size_t)(lane * 8 + i) * 4];
        a0 += gvf * w.x; a1 += gvf * w.y; a2 += gvf * w.z; a3 += gvf * w.w;
    }
#pragma unroll
    for (int off = 32; off; off >>= 1) {
        a0 += __shfl_xor(a0, off);
        a1 += __shfl_xor(a1, off);
        a2 += __shfl_xor(a2, off);
        a3 += __shfl_xor(a3, off);
    }
    if (lane == 0) {
        float m  = fmaxf(fmaxf(a0, a1), fmaxf(a2, a3));
        float e0 = expf(a0 - m), e1 = expf(a1 - m), e2 = expf(a2 - m), e3 = expf(a3 - m);
        float inv = 1.f / (e0 + e1 + e2 + e3);
        *(float4*)&gate[(size_t)wid * 4] = make_float4(e0 * inv, e1 * inv, e2 * inv, e3 * inv);
    }
}

// ---------------------------------------------------------------------------
// combine: out[t,b,o] = sum_j gate[t,b,j] * h2[IDX[t][j], b, o]
// ---------------------------------------------------------------------------
__global__ __launch_bounds__(256) void combine_kernel(
    const bf16_t* __restrict__ h2, const float* __restrict__ gate,
    float* __restrict__ out)
{
    size_t idx = (size_t)blockIdx.x * 256 + threadIdx.x;
    size_t tb  = idx >> 6;
    int    o0  = (int)(idx & 63) * 8;
    int    t   = (int)(tb >> 13);
    size_t b   = tb & (size_t)(B_ - 1);
    const float4 gv = *(const float4*)&gate[tb * 4];
    const bf16x8 v0 = *(const bf16x8*)&h2[((size_t)(2 * t)     * B_ + b) * H2_ + o0];
    const bf16x8 v1 = *(const bf16x8*)&h2[((size_t)(2 * t + 1) * B_ + b) * H2_ + o0];
    const bf16x8 v2 = *(const bf16x8*)&h2[((size_t)4           * B_ + b) * H2_ + o0];
    const bf16x8 v3 = *(const bf16x8*)&h2[((size_t)5           * B_ + b) * H2_ + o0];
    float r[8];
#pragma unroll
    for (int i = 0; i < 8; ++i)
        r[i] = gv.x * (float)v0[i] + gv.y * (float)v1[i]
             + gv.z * (float)v2[i] + gv.w * (float)v3[i];
    float4* op = (float4*)&out[tb * H2_ + o0];
    op[0] = make_float4(r[0], r[1], r[2], r[3]);
    op[1] = make_float4(r[4], r[5], r[6], r[7]);
}

// ---------------------------------------------------------------------------
extern "C" void kernel_launch(void* const* d_in, const int* in_sizes, int n_in,
                              void* d_out, int out_size, void* d_ws, size_t ws_size,
                              hipStream_t stream)
{
    const float* x   = (const float*)d_in[0];
    const float* We1 = (const float*)d_in[1];
    const float* be1 = (const float*)d_in[2];
    const float* We2 = (const float*)d_in[3];
    const float* be2 = (const float*)d_in[4];
    const float* Wg1 = (const float*)d_in[5];
    const float* bg1 = (const float*)d_in[6];
    const float* Wgs = (const float*)d_in[7];
    float* out = (float*)d_out;

    char* ws = (char*)d_ws;
    bf16_t* x_bf  = (bf16_t*)ws;  ws += (size_t)B_ * D_ * 2;             //  33.6 MB
    bf16_t* w1t   = (bf16_t*)ws;  ws += (size_t)7 * H1_ * D_ * 2;        //  29.4 MB (6 experts + gate)
    bf16_t* w2t   = (bf16_t*)ws;  ws += (size_t)E_ * H2_ * H1_ * 2;      //   6.3 MB
    bf16_t* h1    = (bf16_t*)ws;  ws += (size_t)7 * B_ * H1_ * 2;        // 117.4 MB (slice 6 = gate g)
    bf16_t* h2    = (bf16_t*)ws;  ws += (size_t)E_ * B_ * H2_ * 2;       //  50.3 MB
    float*  bias7 = (float*)ws;   ws += (size_t)7 * H1_ * 4;             //  28 KB
    float*  gate  = (float*)ws;   ws += (size_t)T_ * B_ * EC_ * 4;       //   0.3 MB

    bf16_t* wgt = w1t + (size_t)6 * H1_ * D_;   // gate weights = expert slice 6

    // 0) bias concat (d2d async, graph-capture safe)
    hipMemcpyAsync(bias7, be1, (size_t)E_ * H1_ * sizeof(float),
                   hipMemcpyDeviceToDevice, stream);
    hipMemcpyAsync(bias7 + (size_t)E_ * H1_, bg1, (size_t)T_ * G_ * sizeof(float),
                   hipMemcpyDeviceToDevice, stream);

    // 1) casts / transposes
    cast_x_kernel<<<(B_ * D_ / 8) / 256, 256, 0, stream>>>(x, x_bf, B_ * D_ / 8);
    dim3 tb(32, 8);
    transpose_cast_kernel<<<dim3(H1_ / 32, D_ / 32, E_),  tb, 0, stream>>>(We1, w1t, D_,  H1_);
    transpose_cast_kernel<<<dim3(H2_ / 32, H1_ / 32, E_), tb, 0, stream>>>(We2, w2t, H1_, H2_);
    transpose_cast_kernel<<<dim3(G_ / 32, D_ / 32, T_),   tb, 0, stream>>>(Wg1, wgt, D_,  G_);

    // 2) GEMM1 + gate folded: z = 0..5 experts, z = 6 gate (N=1024 each)
    gemm_bn256_bias_relu<<<dim3(H1_ / 256, B_ / 128, 7), 512, 0, stream>>>(
        x_bf, w1t, bias7, h1, B_, H1_, D_, 0LL);
    // 3) GEMM2 over experts 0..5
    gemm_bn256_bias_relu<<<dim3(H2_ / 256, B_ / 128, E_), 512, 0, stream>>>(
        h1, w2t, be2, h2, B_, H2_, H1_, (long long)B_ * H1_);

    // 4) gate softmax + final combine
    gate_kernel<<<(T_ * B_) / 4, 256, 0, stream>>>(h1, Wgs, gate);
    combine_kernel<<<((size_t)T_ * B_ * H2_ / 8) / 256, 256, 0, stream>>>(h2, gate, out);
}